// Round 15
// baseline (293.399 us; speedup 1.0000x reference)
//
#include <hip/hip_runtime.h>
#include <hip/hip_bf16.h>

#define C_DIM 2048
#define NHEAD 16
#define HD 128
#define BB 2
#define TT 2048
#define MM (BB * TT)  // 4096 rows
#define NQT 32        // number of 64-row q tiles per (b,h)
#define N3 (3 * C_DIM)

typedef short short4v __attribute__((ext_vector_type(4)));
typedef short short8v __attribute__((ext_vector_type(8)));
typedef __bf16 bf16x4 __attribute__((ext_vector_type(4)));
typedef __bf16 bf16x8 __attribute__((ext_vector_type(8)));
typedef float f32x4 __attribute__((ext_vector_type(4)));

#define AS1 __attribute__((address_space(1)))
#define AS3 __attribute__((address_space(3)))

#define VMCNT(n) asm volatile("s_waitcnt vmcnt(" #n ")" ::: "memory")

__device__ __forceinline__ void load_lds16(const void* g, void* l) {
  __builtin_amdgcn_global_load_lds((const AS1 void*)g, (AS3 void*)l, 16, 0, 0);
}

__device__ __forceinline__ short f2bf(float f) {
  union { float f; unsigned u; } v; v.f = f;
  unsigned u = v.u;
  u += 0x7FFFu + ((u >> 16) & 1u);  // RNE
  return (short)(u >> 16);
}
__device__ __forceinline__ float bf2f(short s) {
  union { unsigned u; float f; } v;
  v.u = ((unsigned)(unsigned short)s) << 16;
  return v.f;
}

// 2^x via v_exp_f32 (no __exp2f device intrinsic). Non-volatile: CSE-able.
__device__ __forceinline__ float exp2_fast(float x) {
  float r;
  asm("v_exp_f32 %0, %1" : "=v"(r) : "v"(x));
  return r;
}

// ---------------- fp32 -> bf16 convert (x) ----------------
__global__ __launch_bounds__(256) void cvt_x(const float* __restrict__ in,
                                             short* __restrict__ out, int n4) {
  int i = blockIdx.x * 256 + threadIdx.x;
  int stride = gridDim.x * 256;
  for (int idx = i; idx < n4; idx += stride) {
    float4 f = ((const float4*)in)[idx];
    short4v o;
    o[0] = f2bf(f.x); o[1] = f2bf(f.y); o[2] = f2bf(f.z); o[3] = f2bf(f.w);
    ((short4v*)out)[idx] = o;
  }
}

// ---------------- weight transpose + convert (all 4 weights, z-indexed) ----------------
__global__ __launch_bounds__(256) void cvt_w_all(const float* __restrict__ Wq,
                                                 const float* __restrict__ Wk,
                                                 const float* __restrict__ Wv,
                                                 const float* __restrict__ Wo,
                                                 short* __restrict__ Wt) {
  __shared__ float tile[32][33];
  int z = blockIdx.z;
  const float* W = z == 0 ? Wq : z == 1 ? Wk : z == 2 ? Wv : Wo;
  short* dst = Wt + (size_t)z * C_DIM * C_DIM;
  int bx = blockIdx.x;  // n tile
  int by = blockIdx.y;  // k tile
  int lx = threadIdx.x & 31;
  int ly = threadIdx.x >> 5;  // 0..7
#pragma unroll
  for (int j = 0; j < 4; ++j) {
    int r = by * 32 + ly + j * 8;
    tile[ly + j * 8][lx] = W[(size_t)r * C_DIM + bx * 32 + lx];
  }
  __syncthreads();
#pragma unroll
  for (int j = 0; j < 4; ++j) {
    int n = bx * 32 + ly + j * 8;
    dst[(size_t)n * C_DIM + by * 32 + lx] = f2bf(tile[lx][ly + j * 8]);
  }
}

// ---------------- RoPE cos/sin table ----------------
__global__ __launch_bounds__(256) void rope_tab(float2* __restrict__ tab) {
  int idx = blockIdx.x * 256 + threadIdx.x;  // < 2048*64
  int t = idx >> 6, d = idx & 63;
  float inv = expf(-9.210340371976184f * (float)d * (1.0f / 64.0f));
  float a = (float)t * inv;
  tab[idx] = make_float2(cosf(a), sinf(a));
}

// ---------------- deep-pipelined phase GEMM: C = A * Bt^T ----------------
// BM=256, BN=128, BK=64, 512 threads = 8 waves (4M x 2N, 64x64 out each).
// TRIPLE-buffered LDS (144KB, 1 block/CU). Per K-tile: 2 phases (qn halves),
// each phase = {12 ds_reads, stage-issue, s_barrier, 16 MFMA, s_barrier}.
// Stage tile T+2 into buf[(T+2)%3] during tile T's phases: that buffer's
// last reader (tile T-1) finished before a barrier preceding the stage issue
// -- race-free by construction, no vmcnt(0) drain in steady state.
// Counted VMCNT(6) once per K-tile: the youngest tile's 6 loads (A=4, B=2)
// stay in flight; issue-to-wait distance = 2 K-tiles > HBM latency (T4).
template <bool F32OUT>
__global__ __launch_bounds__(512, 2) void gemm3p(const short* __restrict__ A,
                                                 const short* __restrict__ Bt,
                                                 void* __restrict__ Cout,
                                                 int M, int N, int K, int NBN) {
  __shared__ short sA[3][256 * 64];
  __shared__ short sB[3][128 * 64];
  const int tid = threadIdx.x;
  const int lane = tid & 63;
  const int w = tid >> 6;           // 0..7
  const int wm = w >> 1, wn = w & 1;
  const int r = lane & 15, g = lane >> 4;

  const int wg = blockIdx.x;
  const int mb = wg / NBN, nb = wg % NBN;   // nb fastest (R13-verified locality)
  const int m0 = mb * 256, n0 = nb * 128;

  f32x4 acc[4][4] = {};

  // pre-swizzled source staging (rule 21): LDS linear; source k-granule
  // = phys ^ (row&7); read side applies the same XOR. 0 bank conflicts.
  auto stageA = [&](int buf, int kt) {
#pragma unroll
    for (int j2 = 0; j2 < 4; ++j2) {
      int p = j2 * 512 + tid;
      int row = p >> 3;
      int srcg = (p & 7) ^ (row & 7);
      load_lds16(A + (size_t)(m0 + row) * K + kt * 64 + srcg * 8,
                 &sA[buf][(j2 * 512 + w * 64) * 8]);
    }
  };
  auto stageB = [&](int buf, int kt) {
#pragma unroll
    for (int j2 = 0; j2 < 2; ++j2) {
      int p = j2 * 512 + tid;
      int row = p >> 3;
      int srcg = (p & 7) ^ (row & 7);
      load_lds16(Bt + (size_t)(n0 + row) * K + kt * 64 + srcg * 8,
                 &sB[buf][(j2 * 512 + w * 64) * 8]);
    }
  };

  const int NT = K >> 6;  // 32 for K=2048 (NT >= 4 assumed)

  // prologue: stage tiles 0 and 1; wait for tile 0 (tile 1 may stay in flight)
  stageA(0, 0); stageB(0, 0);
  stageA(1, 1); stageB(1, 1);
  VMCNT(6);
  __builtin_amdgcn_s_barrier();

  int bT = 0, bS = 2;  // compute buffer, stage buffer (T+2)
  for (int T = 0; T < NT; ++T) {
    const char* Ab = (const char*)&sA[bT][0];
    const char* Bb = (const char*)&sB[bT][0];
#pragma unroll
    for (int qn = 0; qn < 2; ++qn) {
      // ds-read register subtile: A panel (4 frags x 2 kk) + B half (2 x 2)
      bf16x8 af[4][2], bv[2][2];
#pragma unroll
      for (int fi = 0; fi < 4; ++fi) {
        int row = wm * 64 + fi * 16 + r;
#pragma unroll
        for (int kk = 0; kk < 2; ++kk)
          af[fi][kk] = *(const bf16x8*)(Ab + row * 128 +
                                        (((kk * 4 + g) ^ (row & 7)) << 4));
      }
#pragma unroll
      for (int fj = 0; fj < 2; ++fj) {
        int row = wn * 64 + qn * 32 + fj * 16 + r;
#pragma unroll
        for (int kk = 0; kk < 2; ++kk)
          bv[fj][kk] = *(const bf16x8*)(Bb + row * 128 +
                                        (((kk * 4 + g) ^ (row & 7)) << 4));
      }

      // stage tile T+2 into its (dead) buffer: A at phase 0, B at phase 1
      if (T + 2 < NT) {
        if (qn == 0) stageA(bS, T + 2);
        else         stageB(bS, T + 2);
      }

      __builtin_amdgcn_s_barrier();   // phase start: all reads/stages issued

      __builtin_amdgcn_s_setprio(1);
#pragma unroll
      for (int fi = 0; fi < 4; ++fi)
#pragma unroll
        for (int fj = 0; fj < 2; ++fj)
#pragma unroll
          for (int kk = 0; kk < 2; ++kk)
            acc[fi][qn * 2 + fj] = __builtin_amdgcn_mfma_f32_16x16x32_bf16(
                af[fi][kk], bv[fj][kk], acc[fi][qn * 2 + fj], 0, 0, 0);
      __builtin_amdgcn_s_setprio(0);

      if (qn == 1) {
        if (T == NT - 2) { VMCNT(0); }        // tail: drain last tile's loads
        else if (T < NT - 2) { VMCNT(6); }    // steady: keep 6 in flight
      }
      __builtin_amdgcn_s_barrier();   // phase end: next phase may read staged data
    }
    bT = (bT == 2) ? 0 : bT + 1;
    bS = (bS == 2) ? 0 : bS + 1;
  }

#pragma unroll
  for (int fi = 0; fi < 4; ++fi)
#pragma unroll
    for (int nj = 0; nj < 4; ++nj)
#pragma unroll
      for (int q = 0; q < 4; ++q) {
        int row = m0 + wm * 64 + fi * 16 + g * 4 + q;
        int col = n0 + wn * 64 + nj * 16 + r;
        size_t off = (size_t)row * N + col;
        if constexpr (F32OUT) ((float*)Cout)[off] = acc[fi][nj][q];
        else ((short*)Cout)[off] = f2bf(acc[fi][nj][q]);
      }
}

// ---------------- RoPE + head-major rearrange, vectorized (G13) ----------------
__global__ __launch_bounds__(256) void rope_qk(const short* __restrict__ qkv,
                                               const float2* __restrict__ tab,
                                               short* __restrict__ Qr,
                                               short* __restrict__ Kr) {
  const short* src = qkv + (blockIdx.y ? C_DIM : 0);
  short* dst = blockIdx.y ? Kr : Qr;
  const float qs = blockIdx.y ? 1.0f : 0.12751744f;  // log2(e)/sqrt(128)
  int rid = blockIdx.x * 4 + (threadIdx.x >> 6);     // 0..65535 = bh*2048+t
  int lane = threadIdx.x & 63;
  int t = rid & (TT - 1);
  int bh = rid >> 11;
  int b = bh >> 4, h = bh & 15;
  const short* in = src + ((size_t)(b * TT + t)) * N3 + h * HD;

  int v = *(const int*)(in + 2 * lane);              // bf16 pair at d=2l,2l+1
  int pv = __shfl_xor(v, 32, 64);                    // pair at d^64
  float f0 = bf2f((short)(v & 0xFFFF)),  f1 = bf2f((short)(v >> 16));
  float p0 = bf2f((short)(pv & 0xFFFF)), p1 = bf2f((short)(pv >> 16));
  float4 cst = *(const float4*)(tab + (size_t)t * 64 + ((2 * lane) & 63));
  float s = (lane < 32) ? -1.0f : 1.0f;              // -q2 for first half
  float o0 = (f0 * cst.x + s * p0 * cst.y) * qs;
  float o1 = (f1 * cst.z + s * p1 * cst.w) * qs;
  unsigned out2 = ((unsigned)(unsigned short)f2bf(o0)) |
                  (((unsigned)(unsigned short)f2bf(o1)) << 16);
  *(unsigned*)(dst + (size_t)rid * HD + 2 * lane) = out2;
}

// ---------------- V transpose: fused-QKV [B,T,3C] -> Vt[B,H,D,T] ----------------
__global__ __launch_bounds__(256) void v_tr(const short* __restrict__ qkv,
                                            short* __restrict__ Vt) {
  __shared__ short tl[64][132];
  int bh = blockIdx.y, b = bh >> 4, h = bh & 15;
  int t0 = blockIdx.x * 64;
  int tid = threadIdx.x;
  const short* vsrc = qkv + 2 * C_DIM;
#pragma unroll
  for (int i = 0; i < 4; ++i) {
    int c = i * 256 + tid;
    int row = c >> 4, cc = c & 15;
    short8v v = *(const short8v*)(vsrc + ((size_t)(b * TT + t0 + row)) * N3 + h * HD + cc * 8);
#pragma unroll
    for (int j = 0; j < 8; ++j) tl[row][cc * 8 + j] = v[j];
  }
  __syncthreads();
  int d = tid >> 1, half = tid & 1;
#pragma unroll
  for (int u = 0; u < 4; ++u) {
    short8v ov;
#pragma unroll
    for (int j = 0; j < 8; ++j) ov[j] = tl[half * 32 + u * 8 + j][d];
    *(short8v*)(Vt + ((size_t)bh * HD + d) * TT + t0 + half * 32 + u * 8) = ov;
  }
}

// ---------------- causal flash attention, single q-tile per block ----------------
__global__ __launch_bounds__(256, 3) void attn_one(const short* __restrict__ Qr,
                                                   const short* __restrict__ Kr,
                                                   const short* __restrict__ Vt,
                                                   short* __restrict__ AO) {
  const int bx = blockIdx.x;
  const int j = bx >> 5, bh = bx & 31;
  const int qt = (j & 1) ? (j >> 1) : (NQT - 1 - (j >> 1));
  const int b = bh >> 4, h = bh & 15;
  const int tid = threadIdx.x;
  const int lane = tid & 63;
  const int w = tid >> 6;
  const int r = lane & 15, g = lane >> 4;

  __shared__ short sK[64 * 128];    // swizzled K; reused as output staging
  __shared__ short sV[128 * 64];    // swizzled, [d][key]
  __shared__ short sP[4][16 * 64];  // wave-private P, stride 64, XOR-swizzled

  bf16x8 qf[4];
  {
    const short* qbp = Qr + ((size_t)bh * TT + qt * 64 + w * 16 + r) * HD + g * 8;
#pragma unroll
    for (int s = 0; s < 4; ++s) qf[s] = *(const bf16x8*)(qbp + s * 32);
  }

  f32x4 o[8] = {};
  float m = -1e30f, l = 0.f;

  short8v kreg[4], vreg[4];
  auto stage_load = [&](int kt) {
#pragma unroll
    for (int i = 0; i < 4; ++i) {
      int c = i * 256 + tid;
      kreg[i] = *(const short8v*)(Kr + ((size_t)bh * TT + kt * 64 + (c >> 4)) * HD + (c & 15) * 8);
    }
#pragma unroll
    for (int i = 0; i < 4; ++i) {
      int c = i * 256 + tid;
      vreg[i] = *(const short8v*)(Vt + ((size_t)bh * HD + (c >> 3)) * TT + kt * 64 + (c & 7) * 8);
    }
  };
  auto stage_write = [&]() {
#pragma unroll
    for (int i = 0; i < 4; ++i) {
      int c = i * 256 + tid;
      int row = c >> 4, cc = c & 15;
      int addr = (row * 256 + cc * 16) ^ ((row & 7) << 4);
      *(short8v*)((char*)sK + addr) = kreg[i];
    }
#pragma unroll
    for (int i = 0; i < 4; ++i) {
      int c = i * 256 + tid;
      int row = c >> 3, cc = c & 7;
      int addr = (row * 128 + cc * 16) ^ ((row & 7) << 4);
      *(short8v*)((char*)sV + addr) = vreg[i];
    }
  };

  char* pw = (char*)&sP[w][0];

  stage_load(0);
  stage_write();
  __syncthreads();

  for (int kt = 0; kt <= qt; ++kt) {
    f32x4 sacc[4] = {};
    __builtin_amdgcn_s_setprio(1);
#pragma unroll
    for (int nf = 0; nf < 4; ++nf) {
#pragma unroll
      for (int ss = 0; ss < 4; ++ss) {
        int krow = nf * 16 + r;
        int addr = (krow * 256 + (ss * 32 + g * 8) * 2) ^ ((krow & 7) << 4);
        bf16x8 kf = *(const bf16x8*)((char*)sK + addr);
        sacc[nf] = __builtin_amdgcn_mfma_f32_16x16x32_bf16(kf, qf[ss], sacc[nf], 0, 0, 0);
      }
    }
    __builtin_amdgcn_s_setprio(0);

    if (kt < qt) stage_load(kt + 1);

    if (kt == qt) {
#pragma unroll
      for (int nf = 0; nf < 4; ++nf)
#pragma unroll
        for (int q = 0; q < 4; ++q)
          if (nf * 16 + g * 4 + q > w * 16 + r) sacc[nf][q] = -1e30f;
    }

    float p01 = fmaxf(fmaxf(sacc[0][0], sacc[0][1]), fmaxf(sacc[0][2], sacc[0][3]));
    float p23 = fmaxf(fmaxf(sacc[1][0], sacc[1][1]), fmaxf(sacc[1][2], sacc[1][3]));
    float p45 = fmaxf(fmaxf(sacc[2][0], sacc[2][1]), fmaxf(sacc[2][2], sacc[2][3]));
    float p67 = fmaxf(fmaxf(sacc[3][0], sacc[3][1]), fmaxf(sacc[3][2], sacc[3][3]));
    float pmax = fmaxf(fmaxf(p01, p23), fmaxf(p45, p67));
    pmax = fmaxf(pmax, __shfl_xor(pmax, 16, 64));
    pmax = fmaxf(pmax, __shfl_xor(pmax, 32, 64));

    if (!__all(pmax - m <= 8.0f)) {
      float mnew = fmaxf(m, pmax);
      float alpha = exp2_fast(m - mnew);
      m = mnew;
      l *= alpha;
#pragma unroll
      for (int q = 0; q < 4; ++q) {
        float aq = __shfl(alpha, (g * 4 + q) | (lane & 48), 64);
#pragma unroll
        for (int nf2 = 0; nf2 < 8; ++nf2) o[nf2][q] *= aq;
      }
    }

    float s16 = 0.f;
#pragma unroll
    for (int nf = 0; nf < 4; ++nf) {
      f32x4 pe;
#pragma unroll
      for (int q = 0; q < 4; ++q) pe[q] = exp2_fast(sacc[nf][q] - m);
      s16 += (pe[0] + pe[1]) + (pe[2] + pe[3]);
      int addr = (r * 128 + nf * 32 + g * 8) ^ ((r & 7) << 4);
      *(bf16x4*)(pw + addr) = __builtin_convertvector(pe, bf16x4);
    }
    float rs = s16;
    rs += __shfl_xor(rs, 16, 64);
    rs += __shfl_xor(rs, 32, 64);
    l += rs;

    __builtin_amdgcn_s_setprio(1);
#pragma unroll
    for (int s2 = 0; s2 < 2; ++s2) {
      int paddr = (r * 128 + s2 * 64 + g * 16) ^ ((r & 7) << 4);
      bf16x8 pa = *(const bf16x8*)(pw + paddr);
#pragma unroll
      for (int nf2 = 0; nf2 < 8; ++nf2) {
        int drow = nf2 * 16 + r;
        int addr = (drow * 128 + (s2 * 32 + g * 8) * 2) ^ ((drow & 7) << 4);
        bf16x8 vb = *(const bf16x8*)((char*)sV + addr);
        o[nf2] = __builtin_amdgcn_mfma_f32_16x16x32_bf16(pa, vb, o[nf2], 0, 0, 0);
      }
    }
    __builtin_amdgcn_s_setprio(0);

    __syncthreads();
    if (kt < qt) {
      stage_write();
      __syncthreads();
    }
  }

  float linv = 1.0f / l;
  float lrow[4];
#pragma unroll
  for (int q = 0; q < 4; ++q)
    lrow[q] = __shfl(linv, (g * 4 + q) | (lane & 48), 64);
  short* ow = sK + w * 16 * 128;
#pragma unroll
  for (int nf2 = 0; nf2 < 8; ++nf2)
#pragma unroll
    for (int q = 0; q < 4; ++q)
      ow[(g * 4 + q) * 128 + nf2 * 16 + r] = f2bf(o[nf2][q] * lrow[q]);
  __syncthreads();

#pragma unroll
  for (int ch = 0; ch < 4; ++ch) {
    int c = ch * 256 + tid;
    int orow = c >> 4;
    int ocol = (c & 15) * 8;
    int t = qt * 64 + orow;
    *(short8v*)(AO + ((size_t)b * TT + t) * C_DIM + h * HD + ocol) =
        *(const short8v*)(sK + orow * 128 + ocol);
  }
}

extern "C" void kernel_launch(void* const* d_in, const int* in_sizes, int n_in,
                              void* d_out, int out_size, void* d_ws, size_t ws_size,
                              hipStream_t stream) {
  const float* x  = (const float*)d_in[0];
  const float* Wq = (const float*)d_in[1];
  const float* Wk = (const float*)d_in[2];
  const float* Wv = (const float*)d_in[3];
  const float* Wo = (const float*)d_in[4];

  char* ws = (char*)d_ws;
  size_t off = 0;
  auto take = [&](size_t bytes) {
    char* p = ws + off;
    off += (bytes + 255) & ~(size_t)255;
    return p;
  };
  const size_t xe = (size_t)MM * C_DIM;
  const size_t we = (size_t)C_DIM * C_DIM;
  short* xb   = (short*)take(xe * 2);
  short* wqkv = (short*)take(4 * we * 2);
  short* wot  = wqkv + 3 * we;
  short* qkv  = (short*)take(3 * xe * 2);  // [row][6144]; first xe reused as AO
  short* Qr   = (short*)take(xe * 2);
  short* Kr   = (short*)take(xe * 2);
  short* Vtr  = (short*)take(xe * 2);
  float2* tab = (float2*)take((size_t)TT * 64 * sizeof(float2));
  short* AO   = qkv;

  cvt_x<<<2048, 256, 0, stream>>>(x, xb, (int)(xe / 4));
  cvt_w_all<<<dim3(64, 64, 4), 256, 0, stream>>>(Wq, Wk, Wv, Wo, wqkv);
  rope_tab<<<(TT * 64) / 256, 256, 0, stream>>>(tab);

  // fused QKV GEMM: [4096 x 2048] x [6144 x 2048]^T -> [4096 x 6144]
  // 768 blocks of 256x128 = 3 exact rounds at 1 block/CU
  gemm3p<false><<<768, 512, 0, stream>>>(xb, wqkv, qkv, MM, N3, C_DIM, N3 / 128);

  rope_qk<<<dim3(16384, 2), 256, 0, stream>>>(qkv, tab, Qr, Kr);
  v_tr<<<dim3(32, 32), 256, 0, stream>>>(qkv, Vtr);

  attn_one<<<1024, 256, 0, stream>>>(Qr, Kr, Vtr, AO);

  // output GEMM: 256 blocks = 1 exact round
  gemm3p<true><<<256, 512, 0, stream>>>(AO, wot, d_out, MM, C_DIM, C_DIM, C_DIM / 128);
}

// Round 16
// 263.655 us; speedup vs baseline: 1.1128x; 1.1128x over previous
//
#include <hip/hip_runtime.h>
#include <hip/hip_bf16.h>

#define C_DIM 2048
#define NHEAD 16
#define HD 128
#define BB 2
#define TT 2048
#define MM (BB * TT)  // 4096 rows
#define NQT 32        // number of 64-row q tiles per (b,h)
#define N3 (3 * C_DIM)

typedef short short4v __attribute__((ext_vector_type(4)));
typedef short short8v __attribute__((ext_vector_type(8)));
typedef __bf16 bf16x4 __attribute__((ext_vector_type(4)));
typedef __bf16 bf16x8 __attribute__((ext_vector_type(8)));
typedef float f32x4 __attribute__((ext_vector_type(4)));

#define AS1 __attribute__((address_space(1)))
#define AS3 __attribute__((address_space(3)))

#define VMCNT(n) asm volatile("s_waitcnt vmcnt(" #n ")" ::: "memory")

__device__ __forceinline__ void load_lds16(const void* g, void* l) {
  __builtin_amdgcn_global_load_lds((const AS1 void*)g, (AS3 void*)l, 16, 0, 0);
}

__device__ __forceinline__ short f2bf(float f) {
  union { float f; unsigned u; } v; v.f = f;
  unsigned u = v.u;
  u += 0x7FFFu + ((u >> 16) & 1u);  // RNE
  return (short)(u >> 16);
}
__device__ __forceinline__ float bf2f(short s) {
  union { unsigned u; float f; } v;
  v.u = ((unsigned)(unsigned short)s) << 16;
  return v.f;
}

// 2^x via v_exp_f32 (no __exp2f device intrinsic). Non-volatile: CSE-able.
__device__ __forceinline__ float exp2_fast(float x) {
  float r;
  asm("v_exp_f32 %0, %1" : "=v"(r) : "v"(x));
  return r;
}

// ---------------- fp32 -> bf16 convert (x) ----------------
__global__ __launch_bounds__(256) void cvt_x(const float* __restrict__ in,
                                             short* __restrict__ out, int n4) {
  int i = blockIdx.x * 256 + threadIdx.x;
  int stride = gridDim.x * 256;
  for (int idx = i; idx < n4; idx += stride) {
    float4 f = ((const float4*)in)[idx];
    short4v o;
    o[0] = f2bf(f.x); o[1] = f2bf(f.y); o[2] = f2bf(f.z); o[3] = f2bf(f.w);
    ((short4v*)out)[idx] = o;
  }
}

// ---------------- weight transpose + convert (all 4 weights, z-indexed) ----------------
__global__ __launch_bounds__(256) void cvt_w_all(const float* __restrict__ Wq,
                                                 const float* __restrict__ Wk,
                                                 const float* __restrict__ Wv,
                                                 const float* __restrict__ Wo,
                                                 short* __restrict__ Wt) {
  __shared__ float tile[32][33];
  int z = blockIdx.z;
  const float* W = z == 0 ? Wq : z == 1 ? Wk : z == 2 ? Wv : Wo;
  short* dst = Wt + (size_t)z * C_DIM * C_DIM;
  int bx = blockIdx.x;  // n tile
  int by = blockIdx.y;  // k tile
  int lx = threadIdx.x & 31;
  int ly = threadIdx.x >> 5;  // 0..7
#pragma unroll
  for (int j = 0; j < 4; ++j) {
    int r = by * 32 + ly + j * 8;
    tile[ly + j * 8][lx] = W[(size_t)r * C_DIM + bx * 32 + lx];
  }
  __syncthreads();
#pragma unroll
  for (int j = 0; j < 4; ++j) {
    int n = bx * 32 + ly + j * 8;
    dst[(size_t)n * C_DIM + by * 32 + lx] = f2bf(tile[lx][ly + j * 8]);
  }
}

// ---------------- RoPE cos/sin table ----------------
__global__ __launch_bounds__(256) void rope_tab(float2* __restrict__ tab) {
  int idx = blockIdx.x * 256 + threadIdx.x;  // < 2048*64
  int t = idx >> 6, d = idx & 63;
  float inv = expf(-9.210340371976184f * (float)d * (1.0f / 64.0f));
  float a = (float)t * inv;
  tab[idx] = make_float2(cosf(a), sinf(a));
}

// ---------------- pipelined GEMM with fused epilogue ----------------
// Core = R14-verified gemm8w: BM=BN=128, BK=64, 512 threads = 8 waves
// (2M x 4N, 64x32 out each), double-buffered 64KB LDS, 2 blocks/CU,
// XOR swizzle (0 conflicts), counted VMCNT(4) -- never 0 mid-loop.
// EPI=1: f32 direct store (Wo GEMM).
// EPI=2: fused QKV epilogue. BN==HD so each block's column range is exactly
//   one head of Q, K, or V (z = nb>>4). Stage acc->LDS bf16 tile S[128][130]
//   (stride 130 shorts = conflict-free column reads), then:
//     z<2: RoPE via in-LDS pair reads, coalesced write to Qr/Kr [bh][t][d]
//          (Q pre-scaled by log2e/sqrt(128) for exp2 softmax)
//     z=2: transposed write to Vt [bh][d][t]
//   Replaces the rope_qk + v_tr kernels and the qkv buffer round-trip.
template <int EPI>
__global__ __launch_bounds__(512, 4) void gemm8w(const short* __restrict__ A,
                                                 const short* __restrict__ Bt,
                                                 void* __restrict__ Cout,
                                                 int M, int N, int K, int NBN,
                                                 const float2* __restrict__ tab,
                                                 short* __restrict__ Qr,
                                                 short* __restrict__ Kr,
                                                 short* __restrict__ Vt) {
  __shared__ short smem[4 * 128 * 64];  // 64KB: sA[2] | sB[2]; epilogue reuse
  short (*sA)[128 * 64] = (short(*)[128 * 64])smem;
  short (*sB)[128 * 64] = (short(*)[128 * 64])(smem + 2 * 128 * 64);
  const int tid = threadIdx.x;
  const int lane = tid & 63;
  const int w = tid >> 6;           // 0..7
  const int wm = w >> 2, wn = w & 3;
  const int r = lane & 15, g = lane >> 4;

  const int wg = blockIdx.x;
  const int mb = wg / NBN, nb = wg % NBN;   // nb fastest (R5/R8 locality)
  const int m0 = mb * 128, n0 = nb * 128;

  f32x4 acc[4][2] = {};

  auto stage = [&](int buf, int kt) {
#pragma unroll
    for (int j = 0; j < 2; ++j) {
      int p = j * 512 + tid;
      int row = p >> 3;
      int c16 = (p & 7) ^ (row & 7);
      load_lds16(A + (size_t)(m0 + row) * K + kt * 64 + c16 * 8,
                 &sA[buf][(j * 512 + w * 64) * 8]);
    }
#pragma unroll
    for (int j = 0; j < 2; ++j) {
      int p = j * 512 + tid;
      int row = p >> 3;
      int c16 = (p & 7) ^ (row & 7);
      load_lds16(Bt + (size_t)(n0 + row) * K + kt * 64 + c16 * 8,
                 &sB[buf][(j * 512 + w * 64) * 8]);
    }
  };

  auto compute = [&](int buf) {
#pragma unroll
    for (int kk = 0; kk < 2; ++kk) {
      bf16x8 af[4], bv[2];
#pragma unroll
      for (int m = 0; m < 4; ++m) {
        int row = wm * 64 + m * 16 + r;
        af[m] = *(const bf16x8*)((const char*)&sA[buf][0] + row * 128 +
                                 (((kk * 4 + g) ^ (row & 7)) << 4));
      }
#pragma unroll
      for (int n = 0; n < 2; ++n) {
        int row = wn * 32 + n * 16 + r;
        bv[n] = *(const bf16x8*)((const char*)&sB[buf][0] + row * 128 +
                                 (((kk * 4 + g) ^ (row & 7)) << 4));
      }
      __builtin_amdgcn_s_setprio(1);
#pragma unroll
      for (int m = 0; m < 4; ++m)
#pragma unroll
        for (int n = 0; n < 2; ++n)
          acc[m][n] = __builtin_amdgcn_mfma_f32_16x16x32_bf16(af[m], bv[n], acc[m][n], 0, 0, 0);
      __builtin_amdgcn_s_setprio(0);
    }
  };

  const int NT = K >> 6;  // assumes NT >= 2
  stage(0, 0);
  stage(1, 1);
  VMCNT(4);                       // tile 0 resident (tile 1 in flight)
  __builtin_amdgcn_s_barrier();

  for (int t = 0; t < NT; ++t) {
    const int cur = t & 1;
    compute(cur);
    if (t + 1 < NT) {
      asm volatile("" ::: "memory");
      __builtin_amdgcn_s_barrier();     // all waves done reading buf[cur]
      if (t + 2 < NT) {
        stage(cur, t + 2);              // refill freed buffer
        VMCNT(4);                       // t+1 done; t+2 stays in flight
      } else {
        VMCNT(0);                       // tail: drain t+1
      }
      asm volatile("" ::: "memory");
      __builtin_amdgcn_s_barrier();     // tile t+1 visible to all waves
    }
  }

  if constexpr (EPI == 1) {
    // f32 direct store (Wo GEMM)
#pragma unroll
    for (int m = 0; m < 4; ++m)
#pragma unroll
      for (int n = 0; n < 2; ++n)
#pragma unroll
        for (int q = 0; q < 4; ++q) {
          int row = m0 + wm * 64 + m * 16 + g * 4 + q;
          int col = n0 + wn * 32 + n * 16 + r;
          ((float*)Cout)[(size_t)row * N + col] = acc[m][n][q];
        }
  } else {
    // fused QKV epilogue
    __syncthreads();                    // all waves done with sA/sB
    short* S = smem;                    // [128][130] bf16 tile
#pragma unroll
    for (int m = 0; m < 4; ++m)
#pragma unroll
      for (int n = 0; n < 2; ++n)
#pragma unroll
        for (int q = 0; q < 4; ++q) {
          int row = wm * 64 + m * 16 + g * 4 + q;
          int col = wn * 32 + n * 16 + r;
          S[row * 130 + col] = f2bf(acc[m][n][q]);
        }
    __syncthreads();

    const int z = nb >> 4;              // 0=Q, 1=K, 2=V
    const int h = nb & 15;
    const int b = m0 >> 11;
    const int bh = b * NHEAD + h;
    const int t_base = m0 & (TT - 1);

    if (z < 2) {
      short* dst = (z == 0) ? Qr : Kr;
      const float qs = (z == 0) ? 0.12751744f : 1.0f;  // log2(e)/sqrt(128)
#pragma unroll
      for (int i = 0; i < 4; ++i) {
        int c = i * 512 + tid;          // 2048 chunks of 8 elems
        int row = c >> 4;
        int d0 = (c & 15) * 8;
        int t = t_base + row;
        bool hi = d0 >= 64;
        int dbase = d0 & 63;
        short8v ov;
#pragma unroll
        for (int jj = 0; jj < 8; ++jj) {
          float u  = bf2f(S[row * 130 + d0 + jj]);
          float pu = bf2f(S[row * 130 + ((d0 + jj + 64) & 127)]);
          float2 cs = tab[(size_t)t * 64 + dbase + jj];
          float val = hi ? (u * cs.x + pu * cs.y) : (u * cs.x - pu * cs.y);
          ov[jj] = f2bf(val * qs);
        }
        *(short8v*)(dst + ((size_t)bh * TT + t) * HD + d0) = ov;
      }
    } else {
      // V: transposed write Vt[bh][d][t]
#pragma unroll
      for (int i = 0; i < 4; ++i) {
        int c = i * 512 + tid;
        int d = c >> 4;
        int tc = (c & 15) * 8;
        short8v ov;
#pragma unroll
        for (int jj = 0; jj < 8; ++jj) ov[jj] = S[(tc + jj) * 130 + d];
        *(short8v*)(Vt + ((size_t)bh * HD + d) * TT + t_base + tc) = ov;
      }
    }
  }
}

// ---------------- causal flash attention, single q-tile per block ----------------
// 1024 blocks, anti-triangular dispatch interleave, LB(256,3), 3 blocks/CU.
// AO write staged through sK for coalesced 256B-row stores. (R13/R14 verified)
__global__ __launch_bounds__(256, 3) void attn_one(const short* __restrict__ Qr,
                                                   const short* __restrict__ Kr,
                                                   const short* __restrict__ Vt,
                                                   short* __restrict__ AO) {
  const int bx = blockIdx.x;
  const int j = bx >> 5, bh = bx & 31;
  // long/short interleave: j even -> qt=31-j/2, j odd -> qt=(j-1)/2
  const int qt = (j & 1) ? (j >> 1) : (NQT - 1 - (j >> 1));
  const int b = bh >> 4, h = bh & 15;
  const int tid = threadIdx.x;
  const int lane = tid & 63;
  const int w = tid >> 6;
  const int r = lane & 15, g = lane >> 4;

  __shared__ short sK[64 * 128];    // swizzled K; reused as output staging
  __shared__ short sV[128 * 64];    // swizzled, [d][key]
  __shared__ short sP[4][16 * 64];  // wave-private P, stride 64, XOR-swizzled

  bf16x8 qf[4];
  {
    const short* qbp = Qr + ((size_t)bh * TT + qt * 64 + w * 16 + r) * HD + g * 8;
#pragma unroll
    for (int s = 0; s < 4; ++s) qf[s] = *(const bf16x8*)(qbp + s * 32);
  }

  f32x4 o[8] = {};
  float m = -1e30f, l = 0.f;

  short8v kreg[4], vreg[4];
  auto stage_load = [&](int kt) {
#pragma unroll
    for (int i = 0; i < 4; ++i) {
      int c = i * 256 + tid;
      kreg[i] = *(const short8v*)(Kr + ((size_t)bh * TT + kt * 64 + (c >> 4)) * HD + (c & 15) * 8);
    }
#pragma unroll
    for (int i = 0; i < 4; ++i) {
      int c = i * 256 + tid;
      vreg[i] = *(const short8v*)(Vt + ((size_t)bh * HD + (c >> 3)) * TT + kt * 64 + (c & 7) * 8);
    }
  };
  auto stage_write = [&]() {
#pragma unroll
    for (int i = 0; i < 4; ++i) {
      int c = i * 256 + tid;
      int row = c >> 4, cc = c & 15;
      int addr = (row * 256 + cc * 16) ^ ((row & 7) << 4);
      *(short8v*)((char*)sK + addr) = kreg[i];
    }
#pragma unroll
    for (int i = 0; i < 4; ++i) {
      int c = i * 256 + tid;
      int row = c >> 3, cc = c & 7;
      int addr = (row * 128 + cc * 16) ^ ((row & 7) << 4);
      *(short8v*)((char*)sV + addr) = vreg[i];
    }
  };

  char* pw = (char*)&sP[w][0];

  stage_load(0);
  stage_write();
  __syncthreads();

  for (int kt = 0; kt <= qt; ++kt) {
    f32x4 sacc[4] = {};
    __builtin_amdgcn_s_setprio(1);
#pragma unroll
    for (int nf = 0; nf < 4; ++nf) {
#pragma unroll
      for (int ss = 0; ss < 4; ++ss) {
        int krow = nf * 16 + r;
        int addr = (krow * 256 + (ss * 32 + g * 8) * 2) ^ ((krow & 7) << 4);
        bf16x8 kf = *(const bf16x8*)((char*)sK + addr);
        sacc[nf] = __builtin_amdgcn_mfma_f32_16x16x32_bf16(kf, qf[ss], sacc[nf], 0, 0, 0);
      }
    }
    __builtin_amdgcn_s_setprio(0);

    if (kt < qt) stage_load(kt + 1);

    if (kt == qt) {
#pragma unroll
      for (int nf = 0; nf < 4; ++nf)
#pragma unroll
        for (int q = 0; q < 4; ++q)
          if (nf * 16 + g * 4 + q > w * 16 + r) sacc[nf][q] = -1e30f;
    }

    float p01 = fmaxf(fmaxf(sacc[0][0], sacc[0][1]), fmaxf(sacc[0][2], sacc[0][3]));
    float p23 = fmaxf(fmaxf(sacc[1][0], sacc[1][1]), fmaxf(sacc[1][2], sacc[1][3]));
    float p45 = fmaxf(fmaxf(sacc[2][0], sacc[2][1]), fmaxf(sacc[2][2], sacc[2][3]));
    float p67 = fmaxf(fmaxf(sacc[3][0], sacc[3][1]), fmaxf(sacc[3][2], sacc[3][3]));
    float pmax = fmaxf(fmaxf(p01, p23), fmaxf(p45, p67));
    pmax = fmaxf(pmax, __shfl_xor(pmax, 16, 64));
    pmax = fmaxf(pmax, __shfl_xor(pmax, 32, 64));

    if (!__all(pmax - m <= 8.0f)) {
      float mnew = fmaxf(m, pmax);
      float alpha = exp2_fast(m - mnew);
      m = mnew;
      l *= alpha;
#pragma unroll
      for (int q = 0; q < 4; ++q) {
        float aq = __shfl(alpha, (g * 4 + q) | (lane & 48), 64);
#pragma unroll
        for (int nf2 = 0; nf2 < 8; ++nf2) o[nf2][q] *= aq;
      }
    }

    float s16 = 0.f;
#pragma unroll
    for (int nf = 0; nf < 4; ++nf) {
      f32x4 pe;
#pragma unroll
      for (int q = 0; q < 4; ++q) pe[q] = exp2_fast(sacc[nf][q] - m);
      s16 += (pe[0] + pe[1]) + (pe[2] + pe[3]);
      int addr = (r * 128 + nf * 32 + g * 8) ^ ((r & 7) << 4);
      *(bf16x4*)(pw + addr) = __builtin_convertvector(pe, bf16x4);
    }
    float rs = s16;
    rs += __shfl_xor(rs, 16, 64);
    rs += __shfl_xor(rs, 32, 64);
    l += rs;

    __builtin_amdgcn_s_setprio(1);
#pragma unroll
    for (int s2 = 0; s2 < 2; ++s2) {
      int paddr = (r * 128 + s2 * 64 + g * 16) ^ ((r & 7) << 4);
      bf16x8 pa = *(const bf16x8*)(pw + paddr);
#pragma unroll
      for (int nf2 = 0; nf2 < 8; ++nf2) {
        int drow = nf2 * 16 + r;
        int addr = (drow * 128 + (s2 * 32 + g * 8) * 2) ^ ((drow & 7) << 4);
        bf16x8 vb = *(const bf16x8*)((char*)sV + addr);
        o[nf2] = __builtin_amdgcn_mfma_f32_16x16x32_bf16(pa, vb, o[nf2], 0, 0, 0);
      }
    }
    __builtin_amdgcn_s_setprio(0);

    __syncthreads();
    if (kt < qt) {
      stage_write();
      __syncthreads();
    }
  }

  float linv = 1.0f / l;
  float lrow[4];
#pragma unroll
  for (int q = 0; q < 4; ++q)
    lrow[q] = __shfl(linv, (g * 4 + q) | (lane & 48), 64);
  short* ow = sK + w * 16 * 128;
#pragma unroll
  for (int nf2 = 0; nf2 < 8; ++nf2)
#pragma unroll
    for (int q = 0; q < 4; ++q)
      ow[(g * 4 + q) * 128 + nf2 * 16 + r] = f2bf(o[nf2][q] * lrow[q]);
  __syncthreads();

#pragma unroll
  for (int ch = 0; ch < 4; ++ch) {
    int c = ch * 256 + tid;
    int orow = c >> 4;
    int ocol = (c & 15) * 8;
    int t = qt * 64 + orow;
    *(short8v*)(AO + ((size_t)b * TT + t) * C_DIM + h * HD + ocol) =
        *(const short8v*)(sK + orow * 128 + ocol);
  }
}

extern "C" void kernel_launch(void* const* d_in, const int* in_sizes, int n_in,
                              void* d_out, int out_size, void* d_ws, size_t ws_size,
                              hipStream_t stream) {
  const float* x  = (const float*)d_in[0];
  const float* Wq = (const float*)d_in[1];
  const float* Wk = (const float*)d_in[2];
  const float* Wv = (const float*)d_in[3];
  const float* Wo = (const float*)d_in[4];

  char* ws = (char*)d_ws;
  size_t off = 0;
  auto take = [&](size_t bytes) {
    char* p = ws + off;
    off += (bytes + 255) & ~(size_t)255;
    return p;
  };
  const size_t xe = (size_t)MM * C_DIM;
  const size_t we = (size_t)C_DIM * C_DIM;
  short* xb   = (short*)take(xe * 2);
  short* wqkv = (short*)take(4 * we * 2);   // Wq^T|Wk^T|Wv^T|Wo^T contiguous
  short* wot  = wqkv + 3 * we;
  short* Qr   = (short*)take(xe * 2);
  short* Kr   = (short*)take(xe * 2);
  short* Vtr  = (short*)take(xe * 2);
  short* AO   = (short*)take(xe * 2);
  float2* tab = (float2*)take((size_t)TT * 64 * sizeof(float2));

  cvt_x<<<2048, 256, 0, stream>>>(x, xb, (int)(xe / 4));
  cvt_w_all<<<dim3(64, 64, 4), 256, 0, stream>>>(Wq, Wk, Wv, Wo, wqkv);
  rope_tab<<<(TT * 64) / 256, 256, 0, stream>>>(tab);

  // fused QKV GEMM with rope/transpose epilogue:
  // [4096 x 2048] x [6144 x 2048]^T -> Qr/Kr (rope'd, head-major), Vt (transposed)
  gemm8w<2><<<1536, 512, 0, stream>>>(xb, wqkv, nullptr, MM, N3, C_DIM, N3 / 128,
                                      tab, Qr, Kr, Vtr);

  attn_one<<<1024, 256, 0, stream>>>(Qr, Kr, Vtr, AO);

  // output GEMM: [4096 x 2048] x [2048 x 2048]^T -> f32 [4096 x 2048]
  gemm8w<1><<<512, 512, 0, stream>>>(AO, wot, d_out, MM, C_DIM, C_DIM, C_DIM / 128,
                                     nullptr, nullptr, nullptr, nullptr);
}